// Round 9
// baseline (312.381 us; speedup 1.0000x reference)
//
#include <hip/hip_runtime.h>

// EfficientAdditiveAttention  B=8, L=512, D=128
//
// combined(q,k) = sum_d w_all[d]*tanh(zq_d + zk_d)  -> softmax_k -> @V
// tanh = 1 - 2/(1+e^{2(zq+zk)});  e^{2(zq+zk)} = Eq*Ek, Eq/Ek precomputed by
// the projection kernel. Softmax-invariant constants dropped. With
// w^ = -2*log2e*w_all:  p(k) = exp2( sum_d w^_d / (1+Eq_d*Ek_d) ).
//
// v9: pipe balance. R7 (all-LDS Q-side) was DS-bound; R8 (all-readlane) was
// VALU-bound (40 rl/iter). Split: w^ via 2 LDS bcast b128/iter, Eq via 32
// readlanes/iter -> ~112 VALU + 4 ds per 8-d iter. Epilogue: partial o/psum
// PLAIN STORES to ws slabs (no atomics, no memsets) + one fused
// reduce+normalize kernel; falls back to atomic path if ws is small.

#define BB 8
#define LL 512
#define DD 128
#define NROW (BB*LL)            // 4096 rows
#define MATN (NROW*DD)          // 524288 elements per matrix
#define KSPLIT 8

static constexpr float C1 = 2.8853900817779268f;    // 2*log2(e)
static constexpr float LOG2E = 1.4426950408889634f;
static constexpr float INV_SCALE = 0.08838834764831845f; // 1/sqrt(128)

__device__ __forceinline__ float fast_exp2(float x) { return __builtin_amdgcn_exp2f(x); }
__device__ __forceinline__ float fast_rcp(float x)  { return __builtin_amdgcn_rcpf(x); }

#if __has_builtin(__builtin_amdgcn_readlane)
__device__ __forceinline__ float rl(float v, int l) {
    return __int_as_float(__builtin_amdgcn_readlane(__float_as_int(v), l));
}
#else
__device__ __forceinline__ float rl(float v, int l) { return __shfl(v, l); }
#endif

// ---------------------------------------------------------------------------
// Projection: z = X @ W.T + b; outputs Eq=exp2(C1*z) (m=0), Ek=exp2(C1*z)
// (m=1), V=z (m=2). 32-row x 128-col tiles, 384 blocks x 256 threads.
// ---------------------------------------------------------------------------
__global__ __launch_bounds__(256) void proj_kernel(
    const float* __restrict__ query, const float* __restrict__ key,
    const float* __restrict__ value,
    const float* __restrict__ Wq, const float* __restrict__ bq,
    const float* __restrict__ Wk, const float* __restrict__ bk,
    const float* __restrict__ Wv, const float* __restrict__ bv,
    const float* __restrict__ wd, const float* __restrict__ wsg,
    const float* __restrict__ wtt, float* __restrict__ ws)
{
    __shared__ __align__(16) float Wl[128 * 66];   // 33792 B
    __shared__ __align__(16) float Xl[32 * 66];    //  8448 B

    const int bx = blockIdx.x;
    const int m  = bx >> 7;              // 0:Q 1:K 2:V  (128 row-tiles each)
    const int r0 = (bx & 127) * 32;
    const float* X    = (m == 0) ? query : (m == 1) ? key : value;
    const float* W    = (m == 0) ? Wq    : (m == 1) ? Wk  : Wv;
    const float* bias = (m == 0) ? bq    : (m == 1) ? bk  : bv;
    const int t = threadIdx.x;

    // w^ = -2*log2e*(1/sqrt(D) + wd + wsg + wtt)  -> ws tail (block 0)
    if (bx == 0 && t < 128) {
        ws[(size_t)3 * MATN + t] =
            -2.0f * LOG2E * (INV_SCALE + wd[t] + wsg[t] + wtt[t]);
    }

    const int cg = t & 31;   // cols: cg + 32*j
    const int rg = t >> 5;   // rows: rg*4 + i

    float acc[4][4];
    #pragma unroll
    for (int j = 0; j < 4; ++j) {
        float bj = bias[cg + 32 * j];
        #pragma unroll
        for (int i = 0; i < 4; ++i) acc[i][j] = bj;
    }

    const float4* Wsrc = (const float4*)W;
    const float4* Xsrc = (const float4*)X;

    for (int h = 0; h < 2; ++h) {            // K-dim halves (64 each)
        __syncthreads();
        #pragma unroll
        for (int j = 0; j < 8; ++j) {        // W half: 128 rows x 16 f4
            int g = t + j * 256;
            int c = g >> 4, f4 = g & 15;
            float4 v = Wsrc[c * 32 + h * 16 + f4];
            float* dst = &Wl[c * 66 + f4 * 4];
            *(float2*)dst       = make_float2(v.x, v.y);
            *(float2*)(dst + 2) = make_float2(v.z, v.w);
        }
        #pragma unroll
        for (int j = 0; j < 2; ++j) {        // X half: 32 rows x 16 f4
            int g = t + j * 256;
            int r = g >> 4, f4 = g & 15;
            float4 v = Xsrc[(r0 + r) * 32 + h * 16 + f4];
            float* dst = &Xl[r * 66 + f4 * 4];
            *(float2*)dst       = make_float2(v.x, v.y);
            *(float2*)(dst + 2) = make_float2(v.z, v.w);
        }
        __syncthreads();

        #pragma unroll 4
        for (int dg = 0; dg < 32; ++dg) {
            float2 bf[4];
            #pragma unroll
            for (int j = 0; j < 4; ++j)
                bf[j] = *(const float2*)&Wl[(cg + 32 * j) * 66 + 2 * dg];
            float2 af[4];
            #pragma unroll
            for (int i = 0; i < 4; ++i)
                af[i] = *(const float2*)&Xl[(rg * 4 + i) * 66 + 2 * dg];
            #pragma unroll
            for (int i = 0; i < 4; ++i)
                #pragma unroll
                for (int j = 0; j < 4; ++j)
                    acc[i][j] += af[i].x * bf[j].x + af[i].y * bf[j].y;
        }
    }

    if (m == 2) {
        float* oV = ws + (size_t)2 * MATN;  // V
        #pragma unroll
        for (int i = 0; i < 4; ++i) {
            int r = r0 + rg * 4 + i;
            #pragma unroll
            for (int j = 0; j < 4; ++j)
                oV[(size_t)r * DD + cg + 32 * j] = acc[i][j];
        }
    } else {
        float* oE = ws + (size_t)m * MATN;  // Eq (m=0) or Ek (m=1)
        #pragma unroll
        for (int i = 0; i < 4; ++i) {
            int r = r0 + rg * 4 + i;
            #pragma unroll
            for (int j = 0; j < 4; ++j)
                oE[(size_t)r * DD + cg + 32 * j] = fast_exp2(C1 * acc[i][j]);
        }
    }
}

// ---------------------------------------------------------------------------
// Attention main. 1024 blocks x 512 threads (8 waves). Block = 32 q x one
// 64-k tile (k-split 8). Wave = 4 q. Ek tile in LDS ([k][132] per-lane b128
// rows); w^ in LDS (broadcast b128); Eq distributed in wave VGPRs (8 f/lane),
// fetched via v_readlane. ATOMIC=false: partial o -> part[kx][q][d] plain
// stores, psum -> psumP[kx][q]; ATOMIC=true: legacy atomicAdd path.
// ---------------------------------------------------------------------------
template <bool ATOMIC>
__global__ __launch_bounds__(512, 8) void attn_kernel(
    const float* __restrict__ ws, float* __restrict__ outp,
    float* __restrict__ psump)
{
    __shared__ __align__(16) float Ekt[64 * 132];   // 33792 B
    __shared__ __align__(16) float wl[128];         //   512 B

    const float* Eq  = ws;
    const float* Ek  = ws + (size_t)MATN;
    const float* Vp  = ws + (size_t)2 * MATN;

    const int bx   = blockIdx.x;               // 1024 blocks
    const int qblk = bx >> 3;                  // 0..127  (32 q each)
    const int kx   = bx & 7;                   // k-chunk (64 k)
    const int b    = qblk >> 4;                // 16 q-blocks per batch
    const int wave = __builtin_amdgcn_readfirstlane((int)threadIdx.x >> 6);
    const int lane = threadIdx.x & 63;
    const int qa   = qblk * 32 + wave * 4;     // wave-uniform (global q base)

    // distributed Eq register file: lane L holds Eq flats [8L, 8L+8)
    const float4* EqW = (const float4*)(Eq + (size_t)qa * DD);
    float4 eqa = EqW[2 * lane];
    float4 eqb = EqW[2 * lane + 1];

    {   // stage Ek tile (64 k x 128 d) -> stride-132 rows; w^ -> wl
        const float4* sK = (const float4*)(Ek + (size_t)b * (LL * DD)
                                              + (size_t)kx * 64 * DD);
        #pragma unroll
        for (int r = 0; r < 4; ++r) {
            int g = (int)threadIdx.x + r * 512;    // 0..2047
            int row = g >> 5, c4 = g & 31;
            *(float4*)&Ekt[row * 132 + c4 * 4] = sK[g];
        }
        if (threadIdx.x < 32)
            ((float4*)wl)[threadIdx.x] =
                ((const float4*)(ws + (size_t)3 * MATN))[threadIdx.x];
    }
    __syncthreads();

    // ---- pass A: s(qa..qa+3, k = kx*64+lane); 8 d per step
    const float* krow = &Ekt[lane * 132];
    const float4* wl4 = (const float4*)wl;
    float s0 = 0.f, s1 = 0.f, s2 = 0.f, s3 = 0.f;

    #pragma unroll 4
    for (int ih = 0; ih < 16; ++ih) {          // d = 8*ih .. 8*ih+7
        float4 k0 = *(const float4*)(krow + 8 * ih);      // per-lane b128
        float4 k1 = *(const float4*)(krow + 8 * ih + 4);
        float4 w0 = wl4[2 * ih];                          // bcast b128
        float4 w1 = wl4[2 * ih + 1];
        #define QT(SS, QQ) { \
            const int lq = QQ * 16 + ih; \
            float ax = rl(eqa.x, lq), ay = rl(eqa.y, lq); \
            float az = rl(eqa.z, lq), aw = rl(eqa.w, lq); \
            float e0 = fmaf(ax, k0.x, 1.f), e1 = fmaf(ay, k0.y, 1.f); \
            float e2 = fmaf(az, k0.z, 1.f), e3 = fmaf(aw, k0.w, 1.f); \
            float N01 = fmaf(w0.x, e1, w0.y * e0); \
            float N23 = fmaf(w0.z, e3, w0.w * e2); \
            SS = fmaf(N01, fast_rcp(e0 * e1), SS); \
            SS = fmaf(N23, fast_rcp(e2 * e3), SS); \
            float bx_ = rl(eqb.x, lq), by_ = rl(eqb.y, lq); \
            float bz_ = rl(eqb.z, lq), bw_ = rl(eqb.w, lq); \
            float f0 = fmaf(bx_, k1.x, 1.f), f1 = fmaf(by_, k1.y, 1.f); \
            float f2 = fmaf(bz_, k1.z, 1.f), f3 = fmaf(bw_, k1.w, 1.f); \
            float M01 = fmaf(w1.x, f1, w1.y * f0); \
            float M23 = fmaf(w1.z, f3, w1.w * f2); \
            SS = fmaf(M01, fast_rcp(f0 * f1), SS); \
            SS = fmaf(M23, fast_rcp(f2 * f3), SS); }
        QT(s0, 0) QT(s1, 1) QT(s2, 2) QT(s3, 3)
        #undef QT
    }
    float p0 = fast_exp2(s0);     // lane holds p(qa+qq, k = kx*64+lane)
    float p1 = fast_exp2(s1);
    float p2 = fast_exp2(s2);
    float p3 = fast_exp2(s3);

    // psum over this tile's 64 k
    float t0 = p0, t1 = p1, t2 = p2, t3 = p3;
    #pragma unroll
    for (int off = 32; off; off >>= 1) {
        t0 += __shfl_xor(t0, off);
        t1 += __shfl_xor(t1, off);
        t2 += __shfl_xor(t2, off);
        t3 += __shfl_xor(t3, off);
    }
    if (lane == 0) {
        if (ATOMIC) {
            atomicAdd(&psump[qa + 0], t0);
            atomicAdd(&psump[qa + 1], t1);
            atomicAdd(&psump[qa + 2], t2);
            atomicAdd(&psump[qa + 3], t3);
        } else {
            float* pp = psump + (size_t)kx * NROW + qa;
            pp[0] = t0; pp[1] = t1; pp[2] = t2; pp[3] = t3;
        }
    }

    // ---- pass B: o += p * V ; lane = d-pair, p via readlane (SGPR)
    const float2* __restrict__ Vg =
        (const float2*)(Vp + (size_t)b * (LL * DD) + (size_t)kx * 64 * DD);
    float2 o[4];
    #pragma unroll
    for (int qq = 0; qq < 4; ++qq) o[qq] = make_float2(0.f, 0.f);

    #pragma unroll 16
    for (int e = 0; e < 64; ++e) {
        float2 v = Vg[(size_t)e * 64 + lane];     // coalesced, L1/L2-shared
        float fa = rl(p0, e);
        float fb = rl(p1, e);
        float fc = rl(p2, e);
        float fd = rl(p3, e);
        o[0].x = fmaf(fa, v.x, o[0].x); o[0].y = fmaf(fa, v.y, o[0].y);
        o[1].x = fmaf(fb, v.x, o[1].x); o[1].y = fmaf(fb, v.y, o[1].y);
        o[2].x = fmaf(fc, v.x, o[2].x); o[2].y = fmaf(fc, v.y, o[2].y);
        o[3].x = fmaf(fd, v.x, o[3].x); o[3].y = fmaf(fd, v.y, o[3].y);
    }

    const int d2 = 2 * lane;
    if (ATOMIC) {
        #pragma unroll
        for (int qq = 0; qq < 4; ++qq) {
            atomicAdd(&outp[(size_t)(qa + qq) * DD + d2],     o[qq].x);
            atomicAdd(&outp[(size_t)(qa + qq) * DD + d2 + 1], o[qq].y);
        }
    } else {
        float* base = outp + (size_t)kx * MATN;
        #pragma unroll
        for (int qq = 0; qq < 4; ++qq)
            *(float2*)&base[(size_t)(qa + qq) * DD + d2] = o[qq];
    }
}

// ---------------------------------------------------------------------------
// Fused reduce + normalize: out[q,d] = (sum_kx part[kx][q,d]) / (sum_kx psumP)
// ---------------------------------------------------------------------------
__global__ __launch_bounds__(256) void reduce_kernel(
    const float* __restrict__ part, const float* __restrict__ psumP,
    float* __restrict__ out)
{
    int t = blockIdx.x * 256 + threadIdx.x;    // 262144 float2s
    const float2* p2 = (const float2*)part;
    float2 acc = make_float2(0.f, 0.f);
    #pragma unroll
    for (int kx = 0; kx < KSPLIT; ++kx) {
        float2 v = p2[(size_t)kx * (MATN / 2) + t];
        acc.x += v.x; acc.y += v.y;
    }
    int q = t >> 6;
    float s = 0.f;
    #pragma unroll
    for (int kx = 0; kx < KSPLIT; ++kx) s += psumP[(size_t)kx * NROW + q];
    float inv = fast_rcp(s);
    ((float2*)out)[t] = make_float2(acc.x * inv, acc.y * inv);
}

// ---------------------------------------------------------------------------
__global__ __launch_bounds__(256) void norm_kernel(
    float* __restrict__ out, const float* __restrict__ psumG)
{
    int t = blockIdx.x * 256 + threadIdx.x;    // 262144 float2s
    float2* o2 = (float2*)out;
    int q = t >> 6;
    float inv = fast_rcp(psumG[q]);
    float2 v = o2[t];
    o2[t] = make_float2(v.x * inv, v.y * inv);
}

// ---------------------------------------------------------------------------
extern "C" void kernel_launch(void* const* d_in, const int* in_sizes, int n_in,
                              void* d_out, int out_size, void* d_ws, size_t ws_size,
                              hipStream_t stream) {
    const float* query = (const float*)d_in[0];
    const float* key_  = (const float*)d_in[1];
    const float* value = (const float*)d_in[2];
    const float* Wq    = (const float*)d_in[3];
    const float* bq    = (const float*)d_in[4];
    const float* Wk    = (const float*)d_in[5];
    const float* bk    = (const float*)d_in[6];
    const float* Wv    = (const float*)d_in[7];
    const float* bv    = (const float*)d_in[8];
    const float* wd    = (const float*)d_in[9];
    // d_in[10]/[12]/[14] = b_delta/b_sigma/b_theta: softmax-invariant, dropped
    const float* wsg   = (const float*)d_in[11];
    const float* wtt   = (const float*)d_in[13];
    float* ws = (float*)d_ws;
    float* out = (float*)d_out;

    // ws layout: Eq | Ek | V | w^(128) | psumP(8*NROW) | part(8*MATN)
    const size_t off_psum = (size_t)3 * MATN + 128;
    const size_t off_part = off_psum + (size_t)KSPLIT * NROW;
    const size_t need = (off_part + (size_t)KSPLIT * MATN) * sizeof(float);

    proj_kernel<<<384, 256, 0, stream>>>(query, key_, value,
                                         Wq, bq, Wk, bk, Wv, bv,
                                         wd, wsg, wtt, ws);
    if (ws_size >= need) {
        float* psumP = ws + off_psum;
        float* part  = ws + off_part;
        attn_kernel<false><<<1024, 512, 0, stream>>>(ws, part, psumP);
        reduce_kernel<<<1024, 256, 0, stream>>>(part, psumP, out);
    } else {
        float* psumG = ws + off_psum;
        hipMemsetAsync(out, 0, (size_t)out_size * sizeof(float), stream);
        hipMemsetAsync(psumG, 0, (size_t)NROW * sizeof(float), stream);
        attn_kernel<true><<<1024, 512, 0, stream>>>(ws, out, psumG);
        norm_kernel<<<1024, 256, 0, stream>>>(out, psumG);
    }
}

// Round 10
// 151.239 us; speedup vs baseline: 2.0655x; 2.0655x over previous
//
#include <hip/hip_runtime.h>

// EfficientAdditiveAttention  B=8, L=512, D=128
//
// combined(q,k) = sum_d w_all[d]*tanh(zq_d + zk_d)  -> softmax_k -> @V
// tanh = 1 - 2/(1+e^{2(zq+zk)});  e^{2(zq+zk)} = Eq*Ek, Eq/Ek precomputed by
// the projection kernel. Softmax-invariant constants dropped. With
// w^ = -2*log2e*w_all:  p(k) = exp2( sum_d w^_d / (1+Eq_d*Ek_d) ).
//
// v10 = v9 pipe-split (w^ via LDS bcast, Eq via v_readlane) with the spill
// fixed: no min-waves launch-bounds clause (R9's (512,8) capped VGPR at 64
// and the deep unrolls spilled ~63 MB to scratch), pass A unroll 2, pass B
// bounded 8-load batches. Epilogue: plain stores to part[kx] slabs + fused
// reduce+normalize (no atomics, no memsets); atomic fallback if ws is small.

#define BB 8
#define LL 512
#define DD 128
#define NROW (BB*LL)            // 4096 rows
#define MATN (NROW*DD)          // 524288 elements per matrix
#define KSPLIT 8

static constexpr float C1 = 2.8853900817779268f;    // 2*log2(e)
static constexpr float LOG2E = 1.4426950408889634f;
static constexpr float INV_SCALE = 0.08838834764831845f; // 1/sqrt(128)

__device__ __forceinline__ float fast_exp2(float x) { return __builtin_amdgcn_exp2f(x); }
__device__ __forceinline__ float fast_rcp(float x)  { return __builtin_amdgcn_rcpf(x); }

#if __has_builtin(__builtin_amdgcn_readlane)
__device__ __forceinline__ float rl(float v, int l) {
    return __int_as_float(__builtin_amdgcn_readlane(__float_as_int(v), l));
}
#else
__device__ __forceinline__ float rl(float v, int l) { return __shfl(v, l); }
#endif

// ---------------------------------------------------------------------------
// Projection: z = X @ W.T + b; outputs Eq=exp2(C1*z) (m=0), Ek=exp2(C1*z)
// (m=1), V=z (m=2). 32-row x 128-col tiles, 384 blocks x 256 threads.
// ---------------------------------------------------------------------------
__global__ __launch_bounds__(256) void proj_kernel(
    const float* __restrict__ query, const float* __restrict__ key,
    const float* __restrict__ value,
    const float* __restrict__ Wq, const float* __restrict__ bq,
    const float* __restrict__ Wk, const float* __restrict__ bk,
    const float* __restrict__ Wv, const float* __restrict__ bv,
    const float* __restrict__ wd, const float* __restrict__ wsg,
    const float* __restrict__ wtt, float* __restrict__ ws)
{
    __shared__ __align__(16) float Wl[128 * 66];   // 33792 B
    __shared__ __align__(16) float Xl[32 * 66];    //  8448 B

    const int bx = blockIdx.x;
    const int m  = bx >> 7;              // 0:Q 1:K 2:V  (128 row-tiles each)
    const int r0 = (bx & 127) * 32;
    const float* X    = (m == 0) ? query : (m == 1) ? key : value;
    const float* W    = (m == 0) ? Wq    : (m == 1) ? Wk  : Wv;
    const float* bias = (m == 0) ? bq    : (m == 1) ? bk  : bv;
    const int t = threadIdx.x;

    // w^ = -2*log2e*(1/sqrt(D) + wd + wsg + wtt)  -> ws tail (block 0)
    if (bx == 0 && t < 128) {
        ws[(size_t)3 * MATN + t] =
            -2.0f * LOG2E * (INV_SCALE + wd[t] + wsg[t] + wtt[t]);
    }

    const int cg = t & 31;   // cols: cg + 32*j
    const int rg = t >> 5;   // rows: rg*4 + i

    float acc[4][4];
    #pragma unroll
    for (int j = 0; j < 4; ++j) {
        float bj = bias[cg + 32 * j];
        #pragma unroll
        for (int i = 0; i < 4; ++i) acc[i][j] = bj;
    }

    const float4* Wsrc = (const float4*)W;
    const float4* Xsrc = (const float4*)X;

    for (int h = 0; h < 2; ++h) {            // K-dim halves (64 each)
        __syncthreads();
        #pragma unroll
        for (int j = 0; j < 8; ++j) {        // W half: 128 rows x 16 f4
            int g = t + j * 256;
            int c = g >> 4, f4 = g & 15;
            float4 v = Wsrc[c * 32 + h * 16 + f4];
            float* dst = &Wl[c * 66 + f4 * 4];
            *(float2*)dst       = make_float2(v.x, v.y);
            *(float2*)(dst + 2) = make_float2(v.z, v.w);
        }
        #pragma unroll
        for (int j = 0; j < 2; ++j) {        // X half: 32 rows x 16 f4
            int g = t + j * 256;
            int r = g >> 4, f4 = g & 15;
            float4 v = Xsrc[(r0 + r) * 32 + h * 16 + f4];
            float* dst = &Xl[r * 66 + f4 * 4];
            *(float2*)dst       = make_float2(v.x, v.y);
            *(float2*)(dst + 2) = make_float2(v.z, v.w);
        }
        __syncthreads();

        #pragma unroll 4
        for (int dg = 0; dg < 32; ++dg) {
            float2 bf[4];
            #pragma unroll
            for (int j = 0; j < 4; ++j)
                bf[j] = *(const float2*)&Wl[(cg + 32 * j) * 66 + 2 * dg];
            float2 af[4];
            #pragma unroll
            for (int i = 0; i < 4; ++i)
                af[i] = *(const float2*)&Xl[(rg * 4 + i) * 66 + 2 * dg];
            #pragma unroll
            for (int i = 0; i < 4; ++i)
                #pragma unroll
                for (int j = 0; j < 4; ++j)
                    acc[i][j] += af[i].x * bf[j].x + af[i].y * bf[j].y;
        }
    }

    if (m == 2) {
        float* oV = ws + (size_t)2 * MATN;  // V
        #pragma unroll
        for (int i = 0; i < 4; ++i) {
            int r = r0 + rg * 4 + i;
            #pragma unroll
            for (int j = 0; j < 4; ++j)
                oV[(size_t)r * DD + cg + 32 * j] = acc[i][j];
        }
    } else {
        float* oE = ws + (size_t)m * MATN;  // Eq (m=0) or Ek (m=1)
        #pragma unroll
        for (int i = 0; i < 4; ++i) {
            int r = r0 + rg * 4 + i;
            #pragma unroll
            for (int j = 0; j < 4; ++j)
                oE[(size_t)r * DD + cg + 32 * j] = fast_exp2(C1 * acc[i][j]);
        }
    }
}

// ---------------------------------------------------------------------------
// Attention main. 1024 blocks x 512 threads (8 waves). Block = 32 q x one
// 64-k tile (k-split 8). Wave = 4 q. Ek tile in LDS ([k][132] per-lane b128
// rows); w^ in LDS (broadcast b128); Eq distributed in wave VGPRs (8 f/lane),
// fetched via v_readlane. ATOMIC=false: partial o -> part[kx][q][d] plain
// stores, psum -> psumP[kx][q]; ATOMIC=true: legacy atomicAdd path.
// ---------------------------------------------------------------------------
template <bool ATOMIC>
__global__ __launch_bounds__(512) void attn_kernel(
    const float* __restrict__ ws, float* __restrict__ outp,
    float* __restrict__ psump)
{
    __shared__ __align__(16) float Ekt[64 * 132];   // 33792 B
    __shared__ __align__(16) float wl[128];         //   512 B

    const float* Eq  = ws;
    const float* Ek  = ws + (size_t)MATN;
    const float* Vp  = ws + (size_t)2 * MATN;

    const int bx   = blockIdx.x;               // 1024 blocks
    const int qblk = bx >> 3;                  // 0..127  (32 q each)
    const int kx   = bx & 7;                   // k-chunk (64 k)
    const int b    = qblk >> 4;                // 16 q-blocks per batch
    const int wave = __builtin_amdgcn_readfirstlane((int)threadIdx.x >> 6);
    const int lane = threadIdx.x & 63;
    const int qa   = qblk * 32 + wave * 4;     // wave-uniform (global q base)

    // distributed Eq register file: lane L holds Eq flats [8L, 8L+8)
    const float4* EqW = (const float4*)(Eq + (size_t)qa * DD);
    float4 eqa = EqW[2 * lane];
    float4 eqb = EqW[2 * lane + 1];

    {   // stage Ek tile (64 k x 128 d) -> stride-132 rows; w^ -> wl
        const float4* sK = (const float4*)(Ek + (size_t)b * (LL * DD)
                                              + (size_t)kx * 64 * DD);
        #pragma unroll
        for (int r = 0; r < 4; ++r) {
            int g = (int)threadIdx.x + r * 512;    // 0..2047
            int row = g >> 5, c4 = g & 31;
            *(float4*)&Ekt[row * 132 + c4 * 4] = sK[g];
        }
        if (threadIdx.x < 32)
            ((float4*)wl)[threadIdx.x] =
                ((const float4*)(ws + (size_t)3 * MATN))[threadIdx.x];
    }
    __syncthreads();

    // ---- pass A: s(qa..qa+3, k = kx*64+lane); 8 d per step
    const float* krow = &Ekt[lane * 132];
    const float4* wl4 = (const float4*)wl;
    float s0 = 0.f, s1 = 0.f, s2 = 0.f, s3 = 0.f;

    #pragma unroll 2
    for (int ih = 0; ih < 16; ++ih) {          // d = 8*ih .. 8*ih+7
        float4 k0 = *(const float4*)(krow + 8 * ih);      // per-lane b128
        float4 k1 = *(const float4*)(krow + 8 * ih + 4);
        float4 w0 = wl4[2 * ih];                          // bcast b128
        float4 w1 = wl4[2 * ih + 1];
        #define QT(SS, QQ) { \
            const int lq = QQ * 16 + ih; \
            float ax = rl(eqa.x, lq), ay = rl(eqa.y, lq); \
            float az = rl(eqa.z, lq), aw = rl(eqa.w, lq); \
            float e0 = fmaf(ax, k0.x, 1.f), e1 = fmaf(ay, k0.y, 1.f); \
            float e2 = fmaf(az, k0.z, 1.f), e3 = fmaf(aw, k0.w, 1.f); \
            float N01 = fmaf(w0.x, e1, w0.y * e0); \
            float N23 = fmaf(w0.z, e3, w0.w * e2); \
            SS = fmaf(N01, fast_rcp(e0 * e1), SS); \
            SS = fmaf(N23, fast_rcp(e2 * e3), SS); \
            float bx_ = rl(eqb.x, lq), by_ = rl(eqb.y, lq); \
            float bz_ = rl(eqb.z, lq), bw_ = rl(eqb.w, lq); \
            float f0 = fmaf(bx_, k1.x, 1.f), f1 = fmaf(by_, k1.y, 1.f); \
            float f2 = fmaf(bz_, k1.z, 1.f), f3 = fmaf(bw_, k1.w, 1.f); \
            float M01 = fmaf(w1.x, f1, w1.y * f0); \
            float M23 = fmaf(w1.z, f3, w1.w * f2); \
            SS = fmaf(M01, fast_rcp(f0 * f1), SS); \
            SS = fmaf(M23, fast_rcp(f2 * f3), SS); }
        QT(s0, 0) QT(s1, 1) QT(s2, 2) QT(s3, 3)
        #undef QT
    }
    float p0 = fast_exp2(s0);     // lane holds p(qa+qq, k = kx*64+lane)
    float p1 = fast_exp2(s1);
    float p2 = fast_exp2(s2);
    float p3 = fast_exp2(s3);

    // psum over this tile's 64 k
    float t0 = p0, t1 = p1, t2 = p2, t3 = p3;
    #pragma unroll
    for (int off = 32; off; off >>= 1) {
        t0 += __shfl_xor(t0, off);
        t1 += __shfl_xor(t1, off);
        t2 += __shfl_xor(t2, off);
        t3 += __shfl_xor(t3, off);
    }
    if (lane == 0) {
        if (ATOMIC) {
            atomicAdd(&psump[qa + 0], t0);
            atomicAdd(&psump[qa + 1], t1);
            atomicAdd(&psump[qa + 2], t2);
            atomicAdd(&psump[qa + 3], t3);
        } else {
            float* pp = psump + (size_t)kx * NROW + qa;
            pp[0] = t0; pp[1] = t1; pp[2] = t2; pp[3] = t3;
        }
    }

    // ---- pass B: o += p * V ; lane = d-pair, p via readlane (SGPR);
    // bounded batches of 8 V-loads (8 live float2) to avoid spill.
    const float2* __restrict__ Vg =
        (const float2*)(Vp + (size_t)b * (LL * DD) + (size_t)kx * 64 * DD);
    float2 o[4];
    #pragma unroll
    for (int qq = 0; qq < 4; ++qq) o[qq] = make_float2(0.f, 0.f);

    #pragma unroll
    for (int g = 0; g < 8; ++g) {
        float2 v[8];
        #pragma unroll
        for (int e = 0; e < 8; ++e)
            v[e] = Vg[(size_t)(8 * g + e) * 64 + lane];   // coalesced batch
        #pragma unroll
        for (int e = 0; e < 8; ++e) {
            int kidx = 8 * g + e;
            float fa = rl(p0, kidx);
            float fb = rl(p1, kidx);
            float fc = rl(p2, kidx);
            float fd = rl(p3, kidx);
            o[0].x = fmaf(fa, v[e].x, o[0].x); o[0].y = fmaf(fa, v[e].y, o[0].y);
            o[1].x = fmaf(fb, v[e].x, o[1].x); o[1].y = fmaf(fb, v[e].y, o[1].y);
            o[2].x = fmaf(fc, v[e].x, o[2].x); o[2].y = fmaf(fc, v[e].y, o[2].y);
            o[3].x = fmaf(fd, v[e].x, o[3].x); o[3].y = fmaf(fd, v[e].y, o[3].y);
        }
    }

    const int d2 = 2 * lane;
    if (ATOMIC) {
        #pragma unroll
        for (int qq = 0; qq < 4; ++qq) {
            atomicAdd(&outp[(size_t)(qa + qq) * DD + d2],     o[qq].x);
            atomicAdd(&outp[(size_t)(qa + qq) * DD + d2 + 1], o[qq].y);
        }
    } else {
        float* base = outp + (size_t)kx * MATN;
        #pragma unroll
        for (int qq = 0; qq < 4; ++qq)
            *(float2*)&base[(size_t)(qa + qq) * DD + d2] = o[qq];
    }
}

// ---------------------------------------------------------------------------
// Fused reduce + normalize: out[q,d] = (sum_kx part[kx][q,d]) / (sum_kx psumP)
// ---------------------------------------------------------------------------
__global__ __launch_bounds__(256) void reduce_kernel(
    const float* __restrict__ part, const float* __restrict__ psumP,
    float* __restrict__ out)
{
    int t = blockIdx.x * 256 + threadIdx.x;    // 262144 float2s
    const float2* p2 = (const float2*)part;
    float2 acc = make_float2(0.f, 0.f);
    #pragma unroll
    for (int kx = 0; kx < KSPLIT; ++kx) {
        float2 v = p2[(size_t)kx * (MATN / 2) + t];
        acc.x += v.x; acc.y += v.y;
    }
    int q = t >> 6;
    float s = 0.f;
    #pragma unroll
    for (int kx = 0; kx < KSPLIT; ++kx) s += psumP[(size_t)kx * NROW + q];
    float inv = fast_rcp(s);
    ((float2*)out)[t] = make_float2(acc.x * inv, acc.y * inv);
}

// ---------------------------------------------------------------------------
__global__ __launch_bounds__(256) void norm_kernel(
    float* __restrict__ out, const float* __restrict__ psumG)
{
    int t = blockIdx.x * 256 + threadIdx.x;    // 262144 float2s
    float2* o2 = (float2*)out;
    int q = t >> 6;
    float inv = fast_rcp(psumG[q]);
    float2 v = o2[t];
    o2[t] = make_float2(v.x * inv, v.y * inv);
}

// ---------------------------------------------------------------------------
extern "C" void kernel_launch(void* const* d_in, const int* in_sizes, int n_in,
                              void* d_out, int out_size, void* d_ws, size_t ws_size,
                              hipStream_t stream) {
    const float* query = (const float*)d_in[0];
    const float* key_  = (const float*)d_in[1];
    const float* value = (const float*)d_in[2];
    const float* Wq    = (const float*)d_in[3];
    const float* bq    = (const float*)d_in[4];
    const float* Wk    = (const float*)d_in[5];
    const float* bk    = (const float*)d_in[6];
    const float* Wv    = (const float*)d_in[7];
    const float* bv    = (const float*)d_in[8];
    const float* wd    = (const float*)d_in[9];
    // d_in[10]/[12]/[14] = b_delta/b_sigma/b_theta: softmax-invariant, dropped
    const float* wsg   = (const float*)d_in[11];
    const float* wtt   = (const float*)d_in[13];
    float* ws = (float*)d_ws;
    float* out = (float*)d_out;

    // ws layout: Eq | Ek | V | w^(128) | psumP(8*NROW) | part(8*MATN)
    const size_t off_psum = (size_t)3 * MATN + 128;
    const size_t off_part = off_psum + (size_t)KSPLIT * NROW;
    const size_t need = (off_part + (size_t)KSPLIT * MATN) * sizeof(float);

    proj_kernel<<<384, 256, 0, stream>>>(query, key_, value,
                                         Wq, bq, Wk, bk, Wv, bv,
                                         wd, wsg, wtt, ws);
    if (ws_size >= need) {
        float* psumP = ws + off_psum;
        float* part  = ws + off_part;
        attn_kernel<false><<<1024, 512, 0, stream>>>(ws, part, psumP);
        reduce_kernel<<<1024, 256, 0, stream>>>(part, psumP, out);
    } else {
        float* psumG = ws + off_psum;
        hipMemsetAsync(out, 0, (size_t)out_size * sizeof(float), stream);
        hipMemsetAsync(psumG, 0, (size_t)NROW * sizeof(float), stream);
        attn_kernel<true><<<1024, 512, 0, stream>>>(ws, out, psumG);
        norm_kernel<<<1024, 256, 0, stream>>>(out, psumG);
    }
}

// Round 11
// 151.060 us; speedup vs baseline: 2.0679x; 1.0012x over previous
//
#include <hip/hip_runtime.h>

// EfficientAdditiveAttention  B=8, L=512, D=128
//
// combined(q,k) = sum_d w_all[d]*tanh(zq_d + zk_d)  -> softmax_k -> @V
// tanh = 1 - 2/(1+e^{2(zq+zk)});  e^{2(zq+zk)} = Eq*Ek, Eq/Ek precomputed by
// the projection kernel. Softmax-invariant constants dropped. With
// w^ = -2*log2e*w_all:  p(k) = exp2( sum_d w^_d / (1+Eq_d*Ek_d) ).
//
// v11 = v10 + packed-FP32 math (v_pk_fma_f32 via <2 x float> elementwise fma;
// scalarizes harmlessly if unsupported) + quad-rationalization: the 4 terms
// (d0,d2) and (d1,d3) combine over a common denominator -> 1 rcp per 4 d
// (was 2). Per 8-d iter: ~40 pk + 16 scalar + 8 rcp + 32 readlane + 4 ds
// (was 80 VALU + 16 rcp + 32 rl + 4 ds). Structure unchanged from v10:
// 1024x512, k-split 8, Ek LDS [k][132], w^ LDS bcast, Eq via v_readlane,
// plain-store partials + fused reduce/normalize.

#define BB 8
#define LL 512
#define DD 128
#define NROW (BB*LL)            // 4096 rows
#define MATN (NROW*DD)          // 524288 elements per matrix
#define KSPLIT 8

static constexpr float C1 = 2.8853900817779268f;    // 2*log2(e)
static constexpr float LOG2E = 1.4426950408889634f;
static constexpr float INV_SCALE = 0.08838834764831845f; // 1/sqrt(128)

typedef float v2f __attribute__((ext_vector_type(2)));

__device__ __forceinline__ float fast_exp2(float x) { return __builtin_amdgcn_exp2f(x); }
__device__ __forceinline__ float fast_rcp(float x)  { return __builtin_amdgcn_rcpf(x); }

__device__ __forceinline__ v2f mk2(float a, float b) { v2f r; r.x = a; r.y = b; return r; }

__device__ __forceinline__ v2f fma2(v2f a, v2f b, v2f c) {
#if __has_builtin(__builtin_elementwise_fma)
    return __builtin_elementwise_fma(a, b, c);   // -> v_pk_fma_f32 on CDNA
#else
    v2f r; r.x = fmaf(a.x, b.x, c.x); r.y = fmaf(a.y, b.y, c.y); return r;
#endif
}

#if __has_builtin(__builtin_amdgcn_readlane)
__device__ __forceinline__ float rl(float v, int l) {
    return __int_as_float(__builtin_amdgcn_readlane(__float_as_int(v), l));
}
#else
__device__ __forceinline__ float rl(float v, int l) { return __shfl(v, l); }
#endif

// ---------------------------------------------------------------------------
// Projection: z = X @ W.T + b; outputs Eq=exp2(C1*z) (m=0), Ek=exp2(C1*z)
// (m=1), V=z (m=2). 32-row x 128-col tiles, 384 blocks x 256 threads.
// Inner dot uses packed-f32 accumulators (horizontalized once at the end).
// ---------------------------------------------------------------------------
__global__ __launch_bounds__(256) void proj_kernel(
    const float* __restrict__ query, const float* __restrict__ key,
    const float* __restrict__ value,
    const float* __restrict__ Wq, const float* __restrict__ bq,
    const float* __restrict__ Wk, const float* __restrict__ bk,
    const float* __restrict__ Wv, const float* __restrict__ bv,
    const float* __restrict__ wd, const float* __restrict__ wsg,
    const float* __restrict__ wtt, float* __restrict__ ws)
{
    __shared__ __align__(16) float Wl[128 * 66];   // 33792 B
    __shared__ __align__(16) float Xl[32 * 66];    //  8448 B

    const int bx = blockIdx.x;
    const int m  = bx >> 7;              // 0:Q 1:K 2:V  (128 row-tiles each)
    const int r0 = (bx & 127) * 32;
    const float* X    = (m == 0) ? query : (m == 1) ? key : value;
    const float* W    = (m == 0) ? Wq    : (m == 1) ? Wk  : Wv;
    const float* bias = (m == 0) ? bq    : (m == 1) ? bk  : bv;
    const int t = threadIdx.x;

    // w^ = -2*log2e*(1/sqrt(D) + wd + wsg + wtt)  -> ws tail (block 0)
    if (bx == 0 && t < 128) {
        ws[(size_t)3 * MATN + t] =
            -2.0f * LOG2E * (INV_SCALE + wd[t] + wsg[t] + wtt[t]);
    }

    const int cg = t & 31;   // cols: cg + 32*j
    const int rg = t >> 5;   // rows: rg*4 + i

    v2f acc[4][4];
    #pragma unroll
    for (int j = 0; j < 4; ++j) {
        float bj = bias[cg + 32 * j];
        #pragma unroll
        for (int i = 0; i < 4; ++i) acc[i][j] = mk2(bj, 0.f);
    }

    const float4* Wsrc = (const float4*)W;
    const float4* Xsrc = (const float4*)X;

    for (int h = 0; h < 2; ++h) {            // K-dim halves (64 each)
        __syncthreads();
        #pragma unroll
        for (int j = 0; j < 8; ++j) {        // W half: 128 rows x 16 f4
            int g = t + j * 256;
            int c = g >> 4, f4 = g & 15;
            float4 v = Wsrc[c * 32 + h * 16 + f4];
            float* dst = &Wl[c * 66 + f4 * 4];
            *(float2*)dst       = make_float2(v.x, v.y);
            *(float2*)(dst + 2) = make_float2(v.z, v.w);
        }
        #pragma unroll
        for (int j = 0; j < 2; ++j) {        // X half: 32 rows x 16 f4
            int g = t + j * 256;
            int r = g >> 4, f4 = g & 15;
            float4 v = Xsrc[(r0 + r) * 32 + h * 16 + f4];
            float* dst = &Xl[r * 66 + f4 * 4];
            *(float2*)dst       = make_float2(v.x, v.y);
            *(float2*)(dst + 2) = make_float2(v.z, v.w);
        }
        __syncthreads();

        #pragma unroll 4
        for (int dg = 0; dg < 32; ++dg) {
            v2f bf[4];
            #pragma unroll
            for (int j = 0; j < 4; ++j)
                bf[j] = *(const v2f*)&Wl[(cg + 32 * j) * 66 + 2 * dg];
            v2f af[4];
            #pragma unroll
            for (int i = 0; i < 4; ++i)
                af[i] = *(const v2f*)&Xl[(rg * 4 + i) * 66 + 2 * dg];
            #pragma unroll
            for (int i = 0; i < 4; ++i)
                #pragma unroll
                for (int j = 0; j < 4; ++j)
                    acc[i][j] = fma2(af[i], bf[j], acc[i][j]);   // pk fma
        }
    }

    if (m == 2) {
        float* oV = ws + (size_t)2 * MATN;  // V
        #pragma unroll
        for (int i = 0; i < 4; ++i) {
            int r = r0 + rg * 4 + i;
            #pragma unroll
            for (int j = 0; j < 4; ++j)
                oV[(size_t)r * DD + cg + 32 * j] = acc[i][j].x + acc[i][j].y;
        }
    } else {
        float* oE = ws + (size_t)m * MATN;  // Eq (m=0) or Ek (m=1)
        #pragma unroll
        for (int i = 0; i < 4; ++i) {
            int r = r0 + rg * 4 + i;
            #pragma unroll
            for (int j = 0; j < 4; ++j)
                oE[(size_t)r * DD + cg + 32 * j] =
                    fast_exp2(C1 * (acc[i][j].x + acc[i][j].y));
        }
    }
}

// ---------------------------------------------------------------------------
// Attention main. 1024 blocks x 512 threads (8 waves). Block = 32 q x one
// 64-k tile (k-split 8). Wave = 4 q. Ek tile in LDS ([k][132] per-lane b128
// rows); w^ in LDS (broadcast b128); Eq distributed in wave VGPRs (8 f/lane),
// fetched via v_readlane. Packed-f32 math; quad-rational: pairs (d0,d2) and
// (d1,d3) share one rcp. ATOMIC=false: plain-store partials; else atomicAdd.
// ---------------------------------------------------------------------------
template <bool ATOMIC>
__global__ __launch_bounds__(512) void attn_kernel(
    const float* __restrict__ ws, float* __restrict__ outp,
    float* __restrict__ psump)
{
    __shared__ __align__(16) float Ekt[64 * 132];   // 33792 B
    __shared__ __align__(16) float wl[128];         //   512 B

    const float* Eq  = ws;
    const float* Ek  = ws + (size_t)MATN;
    const float* Vp  = ws + (size_t)2 * MATN;

    const int bx   = blockIdx.x;               // 1024 blocks
    const int qblk = bx >> 3;                  // 0..127  (32 q each)
    const int kx   = bx & 7;                   // k-chunk (64 k)
    const int b    = qblk >> 4;                // 16 q-blocks per batch
    const int wave = __builtin_amdgcn_readfirstlane((int)threadIdx.x >> 6);
    const int lane = threadIdx.x & 63;
    const int qa   = qblk * 32 + wave * 4;     // wave-uniform (global q base)

    // distributed Eq register file: lane L holds Eq flats [8L, 8L+8)
    const float4* EqW = (const float4*)(Eq + (size_t)qa * DD);
    float4 eqa = EqW[2 * lane];
    float4 eqb = EqW[2 * lane + 1];

    {   // stage Ek tile (64 k x 128 d) -> stride-132 rows; w^ -> wl
        const float4* sK = (const float4*)(Ek + (size_t)b * (LL * DD)
                                              + (size_t)kx * 64 * DD);
        #pragma unroll
        for (int r = 0; r < 4; ++r) {
            int g = (int)threadIdx.x + r * 512;    // 0..2047
            int row = g >> 5, c4 = g & 31;
            *(float4*)&Ekt[row * 132 + c4 * 4] = sK[g];
        }
        if (threadIdx.x < 32)
            ((float4*)wl)[threadIdx.x] =
                ((const float4*)(ws + (size_t)3 * MATN))[threadIdx.x];
    }
    __syncthreads();

    // ---- pass A: s(qa..qa+3, k = kx*64+lane); 8 d per step
    const float* krow = &Ekt[lane * 132];
    const float4* wl4 = (const float4*)wl;
    const v2f one2 = mk2(1.f, 1.f);
    float s0 = 0.f, s1 = 0.f, s2 = 0.f, s3 = 0.f;

    #pragma unroll 2
    for (int ih = 0; ih < 16; ++ih) {          // d = 8*ih .. 8*ih+7
        v2f K01 = *(const v2f*)(krow + 8 * ih);       // (k_d0, k_d1)
        v2f K23 = *(const v2f*)(krow + 8 * ih + 2);   // (k_d2, k_d3)
        v2f K45 = *(const v2f*)(krow + 8 * ih + 4);
        v2f K67 = *(const v2f*)(krow + 8 * ih + 6);
        float4 w0 = wl4[2 * ih];                      // bcast b128
        float4 w1 = wl4[2 * ih + 1];
        v2f Wa = mk2(w0.x, w0.y), Wb = mk2(w0.z, w0.w);
        v2f Wc = mk2(w1.x, w1.y), Wd = mk2(w1.z, w1.w);
        // quad-rational: terms (d0,d2) & (d1,d3) share one rcp:
        //   NUM = (w0*e2 + w2*e0, w1*e3 + w3*e1), DEN = (e0*e2, e1*e3)
        //   s += (NUM.x*DEN.y + NUM.y*DEN.x) * rcp(DEN.x*DEN.y)
        #define QT(SS, QQ) { \
            const int lq = QQ * 16 + ih; \
            v2f A  = mk2(rl(eqa.x, lq), rl(eqa.y, lq)); \
            v2f Bv = mk2(rl(eqa.z, lq), rl(eqa.w, lq)); \
            v2f Elo = fma2(A,  K01, one2); \
            v2f Ehi = fma2(Bv, K23, one2); \
            v2f NUM = fma2(Wa, Ehi, Wb * Elo); \
            v2f DEN = Elo * Ehi; \
            SS = fmaf(fmaf(NUM.x, DEN.y, NUM.y * DEN.x), \
                      fast_rcp(DEN.x * DEN.y), SS); \
            v2f C  = mk2(rl(eqb.x, lq), rl(eqb.y, lq)); \
            v2f Dv = mk2(rl(eqb.z, lq), rl(eqb.w, lq)); \
            Elo = fma2(C,  K45, one2); \
            Ehi = fma2(Dv, K67, one2); \
            NUM = fma2(Wc, Ehi, Wd * Elo); \
            DEN = Elo * Ehi; \
            SS = fmaf(fmaf(NUM.x, DEN.y, NUM.y * DEN.x), \
                      fast_rcp(DEN.x * DEN.y), SS); }
        QT(s0, 0) QT(s1, 1) QT(s2, 2) QT(s3, 3)
        #undef QT
    }
    float p0 = fast_exp2(s0);     // lane holds p(qa+qq, k = kx*64+lane)
    float p1 = fast_exp2(s1);
    float p2 = fast_exp2(s2);
    float p3 = fast_exp2(s3);

    // psum over this tile's 64 k
    float t0 = p0, t1 = p1, t2 = p2, t3 = p3;
    #pragma unroll
    for (int off = 32; off; off >>= 1) {
        t0 += __shfl_xor(t0, off);
        t1 += __shfl_xor(t1, off);
        t2 += __shfl_xor(t2, off);
        t3 += __shfl_xor(t3, off);
    }
    if (lane == 0) {
        if (ATOMIC) {
            atomicAdd(&psump[qa + 0], t0);
            atomicAdd(&psump[qa + 1], t1);
            atomicAdd(&psump[qa + 2], t2);
            atomicAdd(&psump[qa + 3], t3);
        } else {
            float* pp = psump + (size_t)kx * NROW + qa;
            pp[0] = t0; pp[1] = t1; pp[2] = t2; pp[3] = t3;
        }
    }

    // ---- pass B: o += p * V ; lane = d-pair, p via readlane, pk fma;
    // bounded batches of 8 V-loads (8 live v2f) to avoid spill.
    const v2f* __restrict__ Vg =
        (const v2f*)(Vp + (size_t)b * (LL * DD) + (size_t)kx * 64 * DD);
    v2f o[4];
    #pragma unroll
    for (int qq = 0; qq < 4; ++qq) o[qq] = mk2(0.f, 0.f);

    #pragma unroll
    for (int g = 0; g < 8; ++g) {
        v2f v[8];
        #pragma unroll
        for (int e = 0; e < 8; ++e)
            v[e] = Vg[(size_t)(8 * g + e) * 64 + lane];   // coalesced batch
        #pragma unroll
        for (int e = 0; e < 8; ++e) {
            int kidx = 8 * g + e;
            float fa = rl(p0, kidx);
            float fb = rl(p1, kidx);
            float fc = rl(p2, kidx);
            float fd = rl(p3, kidx);
            o[0] = fma2(mk2(fa, fa), v[e], o[0]);
            o[1] = fma2(mk2(fb, fb), v[e], o[1]);
            o[2] = fma2(mk2(fc, fc), v[e], o[2]);
            o[3] = fma2(mk2(fd, fd), v[e], o[3]);
        }
    }

    const int d2 = 2 * lane;
    if (ATOMIC) {
        #pragma unroll
        for (int qq = 0; qq < 4; ++qq) {
            atomicAdd(&outp[(size_t)(qa + qq) * DD + d2],     o[qq].x);
            atomicAdd(&outp[(size_t)(qa + qq) * DD + d2 + 1], o[qq].y);
        }
    } else {
        float* base = outp + (size_t)kx * MATN;
        #pragma unroll
        for (int qq = 0; qq < 4; ++qq)
            *(float2*)&base[(size_t)(qa + qq) * DD + d2] =
                make_float2(o[qq].x, o[qq].y);
    }
}

// ---------------------------------------------------------------------------
// Fused reduce + normalize: out[q,d] = (sum_kx part[kx][q,d]) / (sum_kx psumP)
// ---------------------------------------------------------------------------
__global__ __launch_bounds__(256) void reduce_kernel(
    const float* __restrict__ part, const float* __restrict__ psumP,
    float* __restrict__ out)
{
    int t = blockIdx.x * 256 + threadIdx.x;    // 262144 float2s
    const float2* p2 = (const float2*)part;
    float2 acc = make_float2(0.f, 0.f);
    #pragma unroll
    for (int kx = 0; kx < KSPLIT; ++kx) {
        float2 v = p2[(size_t)kx * (MATN / 2) + t];
        acc.x += v.x; acc.y += v.y;
    }
    int q = t >> 6;
    float s = 0.f;
    #pragma unroll
    for (int kx = 0; kx < KSPLIT; ++kx) s += psumP[(size_t)kx * NROW + q];
    float inv = fast_rcp(s);
    ((float2*)out)[t] = make_float2(acc.x * inv, acc.y * inv);
}

// ---------------------------------------------------------------------------
__global__ __launch_bounds__(256) void norm_kernel(
    float* __restrict__ out, const float* __restrict__ psumG)
{
    int t = blockIdx.x * 256 + threadIdx.x;    // 262144 float2s
    float2* o2 = (float2*)out;
    int q = t >> 6;
    float inv = fast_rcp(psumG[q]);
    float2 v = o2[t];
    o2[t] = make_float2(v.x * inv, v.y * inv);
}

// ---------------------------------------------------------------------------
extern "C" void kernel_launch(void* const* d_in, const int* in_sizes, int n_in,
                              void* d_out, int out_size, void* d_ws, size_t ws_size,
                              hipStream_t stream) {
    const float* query = (const float*)d_in[0];
    const float* key_  = (const float*)d_in[1];
    const float* value = (const float*)d_in[2];
    const float* Wq    = (const float*)d_in[3];
    const float* bq    = (const float*)d_in[4];
    const float* Wk    = (const float*)d_in[5];
    const float* bk    = (const float*)d_in[6];
    const float* Wv    = (const float*)d_in[7];
    const float* bv    = (const float*)d_in[8];
    const float* wd    = (const float*)d_in[9];
    // d_in[10]/[12]/[14] = b_delta/b_sigma/b_theta: softmax-invariant, dropped
    const float* wsg   = (const float*)d_in[11];
    const float* wtt   = (const float*)d_in[13];
    float* ws = (float*)d_ws;
    float* out = (float*)d_out;

    // ws layout: Eq | Ek | V | w^(128) | psumP(8*NROW) | part(8*MATN)
    const size_t off_psum = (size_t)3 * MATN + 128;
    const size_t off_part = off_psum + (size_t)KSPLIT * NROW;
    const size_t need = (off_part + (size_t)KSPLIT * MATN) * sizeof(float);

    proj_kernel<<<384, 256, 0, stream>>>(query, key_, value,
                                         Wq, bq, Wk, bk, Wv, bv,
                                         wd, wsg, wtt, ws);
    if (ws_size >= need) {
        float* psumP = ws + off_psum;
        float* part  = ws + off_part;
        attn_kernel<false><<<1024, 512, 0, stream>>>(ws, part, psumP);
        reduce_kernel<<<1024, 256, 0, stream>>>(part, psumP, out);
    } else {
        float* psumG = ws + off_psum;
        hipMemsetAsync(out, 0, (size_t)out_size * sizeof(float), stream);
        hipMemsetAsync(psumG, 0, (size_t)NROW * sizeof(float), stream);
        attn_kernel<true><<<1024, 512, 0, stream>>>(ws, out, psumG);
        norm_kernel<<<1024, 256, 0, stream>>>(out, psumG);
    }
}

// Round 12
// 147.389 us; speedup vs baseline: 2.1194x; 1.0249x over previous
//
#include <hip/hip_runtime.h>

// EfficientAdditiveAttention  B=8, L=512, D=128
//
// combined(q,k) = sum_d w_all[d]*tanh(zq_d + zk_d)  -> softmax_k -> @V
// tanh = 1 - 2/(1+e^{2(zq+zk)});  e^{2(zq+zk)} = Eq*Ek, Eq/Ek precomputed by
// the projection kernel. Softmax-invariant constants dropped. With
// w^ = -2*log2e*w_all:  p(k) = exp2( sum_d w^_d / (1+Eq_d*Ek_d) ).
//
// v12 = R11 proj (v2f packed math, ~5us faster than scalar) + R10 attn
// (scalar hot loop, best at 53.5us) with SCALAR quad-rationalization:
// 4 d-terms share one rcp ->
//   e_i = fma(Eq,Ek,1); d01=e0*e1; d23=e2*e3;
//   n01 = w0*e1+w1*e0; n23 = w2*e3+w3*e2;
//   s += (n01*d23 + n23*d01) * rcp(d01*d23)
// 8 rcp/iter (was 16) at +2 VALU per 4-d group. Everything else R10-exact.

#define BB 8
#define LL 512
#define DD 128
#define NROW (BB*LL)            // 4096 rows
#define MATN (NROW*DD)          // 524288 elements per matrix
#define KSPLIT 8

static constexpr float C1 = 2.8853900817779268f;    // 2*log2(e)
static constexpr float LOG2E = 1.4426950408889634f;
static constexpr float INV_SCALE = 0.08838834764831845f; // 1/sqrt(128)

typedef float v2f __attribute__((ext_vector_type(2)));

__device__ __forceinline__ float fast_exp2(float x) { return __builtin_amdgcn_exp2f(x); }
__device__ __forceinline__ float fast_rcp(float x)  { return __builtin_amdgcn_rcpf(x); }

__device__ __forceinline__ v2f mk2(float a, float b) { v2f r; r.x = a; r.y = b; return r; }

__device__ __forceinline__ v2f fma2(v2f a, v2f b, v2f c) {
#if __has_builtin(__builtin_elementwise_fma)
    return __builtin_elementwise_fma(a, b, c);
#else
    v2f r; r.x = fmaf(a.x, b.x, c.x); r.y = fmaf(a.y, b.y, c.y); return r;
#endif
}

#if __has_builtin(__builtin_amdgcn_readlane)
__device__ __forceinline__ float rl(float v, int l) {
    return __int_as_float(__builtin_amdgcn_readlane(__float_as_int(v), l));
}
#else
__device__ __forceinline__ float rl(float v, int l) { return __shfl(v, l); }
#endif

// ---------------------------------------------------------------------------
// Projection (R11 form): z = X @ W.T + b; outputs Eq=exp2(C1*z) (m=0),
// Ek=exp2(C1*z) (m=1), V=z (m=2). 32x128 tiles, 384 blocks x 256 threads,
// packed-f32 inner dot.
// ---------------------------------------------------------------------------
__global__ __launch_bounds__(256) void proj_kernel(
    const float* __restrict__ query, const float* __restrict__ key,
    const float* __restrict__ value,
    const float* __restrict__ Wq, const float* __restrict__ bq,
    const float* __restrict__ Wk, const float* __restrict__ bk,
    const float* __restrict__ Wv, const float* __restrict__ bv,
    const float* __restrict__ wd, const float* __restrict__ wsg,
    const float* __restrict__ wtt, float* __restrict__ ws)
{
    __shared__ __align__(16) float Wl[128 * 66];   // 33792 B
    __shared__ __align__(16) float Xl[32 * 66];    //  8448 B

    const int bx = blockIdx.x;
    const int m  = bx >> 7;              // 0:Q 1:K 2:V  (128 row-tiles each)
    const int r0 = (bx & 127) * 32;
    const float* X    = (m == 0) ? query : (m == 1) ? key : value;
    const float* W    = (m == 0) ? Wq    : (m == 1) ? Wk  : Wv;
    const float* bias = (m == 0) ? bq    : (m == 1) ? bk  : bv;
    const int t = threadIdx.x;

    // w^ = -2*log2e*(1/sqrt(D) + wd + wsg + wtt)  -> ws tail (block 0)
    if (bx == 0 && t < 128) {
        ws[(size_t)3 * MATN + t] =
            -2.0f * LOG2E * (INV_SCALE + wd[t] + wsg[t] + wtt[t]);
    }

    const int cg = t & 31;   // cols: cg + 32*j
    const int rg = t >> 5;   // rows: rg*4 + i

    v2f acc[4][4];
    #pragma unroll
    for (int j = 0; j < 4; ++j) {
        float bj = bias[cg + 32 * j];
        #pragma unroll
        for (int i = 0; i < 4; ++i) acc[i][j] = mk2(bj, 0.f);
    }

    const float4* Wsrc = (const float4*)W;
    const float4* Xsrc = (const float4*)X;

    for (int h = 0; h < 2; ++h) {            // K-dim halves (64 each)
        __syncthreads();
        #pragma unroll
        for (int j = 0; j < 8; ++j) {        // W half: 128 rows x 16 f4
            int g = t + j * 256;
            int c = g >> 4, f4 = g & 15;
            float4 v = Wsrc[c * 32 + h * 16 + f4];
            float* dst = &Wl[c * 66 + f4 * 4];
            *(float2*)dst       = make_float2(v.x, v.y);
            *(float2*)(dst + 2) = make_float2(v.z, v.w);
        }
        #pragma unroll
        for (int j = 0; j < 2; ++j) {        // X half: 32 rows x 16 f4
            int g = t + j * 256;
            int r = g >> 4, f4 = g & 15;
            float4 v = Xsrc[(r0 + r) * 32 + h * 16 + f4];
            float* dst = &Xl[r * 66 + f4 * 4];
            *(float2*)dst       = make_float2(v.x, v.y);
            *(float2*)(dst + 2) = make_float2(v.z, v.w);
        }
        __syncthreads();

        #pragma unroll 4
        for (int dg = 0; dg < 32; ++dg) {
            v2f bf[4];
            #pragma unroll
            for (int j = 0; j < 4; ++j)
                bf[j] = *(const v2f*)&Wl[(cg + 32 * j) * 66 + 2 * dg];
            v2f af[4];
            #pragma unroll
            for (int i = 0; i < 4; ++i)
                af[i] = *(const v2f*)&Xl[(rg * 4 + i) * 66 + 2 * dg];
            #pragma unroll
            for (int i = 0; i < 4; ++i)
                #pragma unroll
                for (int j = 0; j < 4; ++j)
                    acc[i][j] = fma2(af[i], bf[j], acc[i][j]);
        }
    }

    if (m == 2) {
        float* oV = ws + (size_t)2 * MATN;  // V
        #pragma unroll
        for (int i = 0; i < 4; ++i) {
            int r = r0 + rg * 4 + i;
            #pragma unroll
            for (int j = 0; j < 4; ++j)
                oV[(size_t)r * DD + cg + 32 * j] = acc[i][j].x + acc[i][j].y;
        }
    } else {
        float* oE = ws + (size_t)m * MATN;  // Eq (m=0) or Ek (m=1)
        #pragma unroll
        for (int i = 0; i < 4; ++i) {
            int r = r0 + rg * 4 + i;
            #pragma unroll
            for (int j = 0; j < 4; ++j)
                oE[(size_t)r * DD + cg + 32 * j] =
                    fast_exp2(C1 * (acc[i][j].x + acc[i][j].y));
        }
    }
}

// ---------------------------------------------------------------------------
// Attention main (R10 structure). 1024 blocks x 512 threads. Block = 32 q x
// one 64-k tile. Wave = 4 q. Ek in LDS [k][132]; w^ in LDS (bcast b128);
// Eq distributed in wave VGPRs via v_readlane. Scalar quad-rational pass A.
// ATOMIC=false: plain-store partials; ATOMIC=true: atomicAdd fallback.
// ---------------------------------------------------------------------------
template <bool ATOMIC>
__global__ __launch_bounds__(512) void attn_kernel(
    const float* __restrict__ ws, float* __restrict__ outp,
    float* __restrict__ psump)
{
    __shared__ __align__(16) float Ekt[64 * 132];   // 33792 B
    __shared__ __align__(16) float wl[128];         //   512 B

    const float* Eq  = ws;
    const float* Ek  = ws + (size_t)MATN;
    const float* Vp  = ws + (size_t)2 * MATN;

    const int bx   = blockIdx.x;               // 1024 blocks
    const int qblk = bx >> 3;                  // 0..127  (32 q each)
    const int kx   = bx & 7;                   // k-chunk (64 k)
    const int b    = qblk >> 4;                // 16 q-blocks per batch
    const int wave = __builtin_amdgcn_readfirstlane((int)threadIdx.x >> 6);
    const int lane = threadIdx.x & 63;
    const int qa   = qblk * 32 + wave * 4;     // wave-uniform (global q base)

    // distributed Eq register file: lane L holds Eq flats [8L, 8L+8)
    const float4* EqW = (const float4*)(Eq + (size_t)qa * DD);
    float4 eqa = EqW[2 * lane];
    float4 eqb = EqW[2 * lane + 1];

    {   // stage Ek tile (64 k x 128 d) -> stride-132 rows; w^ -> wl
        const float4* sK = (const float4*)(Ek + (size_t)b * (LL * DD)
                                              + (size_t)kx * 64 * DD);
        #pragma unroll
        for (int r = 0; r < 4; ++r) {
            int g = (int)threadIdx.x + r * 512;    // 0..2047
            int row = g >> 5, c4 = g & 31;
            *(float4*)&Ekt[row * 132 + c4 * 4] = sK[g];
        }
        if (threadIdx.x < 32)
            ((float4*)wl)[threadIdx.x] =
                ((const float4*)(ws + (size_t)3 * MATN))[threadIdx.x];
    }
    __syncthreads();

    // ---- pass A: s(qa..qa+3, k = kx*64+lane); 8 d per step
    const float* krow = &Ekt[lane * 132];
    const float4* wl4 = (const float4*)wl;
    float s0 = 0.f, s1 = 0.f, s2 = 0.f, s3 = 0.f;

    #pragma unroll 2
    for (int ih = 0; ih < 16; ++ih) {          // d = 8*ih .. 8*ih+7
        float4 k0 = *(const float4*)(krow + 8 * ih);      // per-lane b128
        float4 k1 = *(const float4*)(krow + 8 * ih + 4);
        float4 w0 = wl4[2 * ih];                          // bcast b128
        float4 w1 = wl4[2 * ih + 1];
        // quad-rational: 4 d-terms share one rcp
        #define QT(SS, QQ) { \
            const int lq = QQ * 16 + ih; \
            float ax = rl(eqa.x, lq), ay = rl(eqa.y, lq); \
            float az = rl(eqa.z, lq), aw = rl(eqa.w, lq); \
            float e0 = fmaf(ax, k0.x, 1.f), e1 = fmaf(ay, k0.y, 1.f); \
            float e2 = fmaf(az, k0.z, 1.f), e3 = fmaf(aw, k0.w, 1.f); \
            float d01 = e0 * e1, d23 = e2 * e3; \
            float n01 = fmaf(w0.x, e1, w0.y * e0); \
            float n23 = fmaf(w0.z, e3, w0.w * e2); \
            float num = fmaf(n01, d23, n23 * d01); \
            SS = fmaf(num, fast_rcp(d01 * d23), SS); \
            float bx_ = rl(eqb.x, lq), by_ = rl(eqb.y, lq); \
            float bz_ = rl(eqb.z, lq), bw_ = rl(eqb.w, lq); \
            float f0 = fmaf(bx_, k1.x, 1.f), f1 = fmaf(by_, k1.y, 1.f); \
            float f2 = fmaf(bz_, k1.z, 1.f), f3 = fmaf(bw_, k1.w, 1.f); \
            float g01 = f0 * f1, g23 = f2 * f3; \
            float m01 = fmaf(w1.x, f1, w1.y * f0); \
            float m23 = fmaf(w1.z, f3, w1.w * f2); \
            float mum = fmaf(m01, g23, m23 * g01); \
            SS = fmaf(mum, fast_rcp(g01 * g23), SS); }
        QT(s0, 0) QT(s1, 1) QT(s2, 2) QT(s3, 3)
        #undef QT
    }
    float p0 = fast_exp2(s0);     // lane holds p(qa+qq, k = kx*64+lane)
    float p1 = fast_exp2(s1);
    float p2 = fast_exp2(s2);
    float p3 = fast_exp2(s3);

    // psum over this tile's 64 k
    float t0 = p0, t1 = p1, t2 = p2, t3 = p3;
    #pragma unroll
    for (int off = 32; off; off >>= 1) {
        t0 += __shfl_xor(t0, off);
        t1 += __shfl_xor(t1, off);
        t2 += __shfl_xor(t2, off);
        t3 += __shfl_xor(t3, off);
    }
    if (lane == 0) {
        if (ATOMIC) {
            atomicAdd(&psump[qa + 0], t0);
            atomicAdd(&psump[qa + 1], t1);
            atomicAdd(&psump[qa + 2], t2);
            atomicAdd(&psump[qa + 3], t3);
        } else {
            float* pp = psump + (size_t)kx * NROW + qa;
            pp[0] = t0; pp[1] = t1; pp[2] = t2; pp[3] = t3;
        }
    }

    // ---- pass B: o += p * V ; lane = d-pair, p via readlane (SGPR);
    // bounded batches of 8 V-loads (8 live float2) to avoid spill.
    const float2* __restrict__ Vg =
        (const float2*)(Vp + (size_t)b * (LL * DD) + (size_t)kx * 64 * DD);
    float2 o[4];
    #pragma unroll
    for (int qq = 0; qq < 4; ++qq) o[qq] = make_float2(0.f, 0.f);

    #pragma unroll
    for (int g = 0; g < 8; ++g) {
        float2 v[8];
        #pragma unroll
        for (int e = 0; e < 8; ++e)
            v[e] = Vg[(size_t)(8 * g + e) * 64 + lane];   // coalesced batch
        #pragma unroll
        for (int e = 0; e < 8; ++e) {
            int kidx = 8 * g + e;
            float fa = rl(p0, kidx);
            float fb = rl(p1, kidx);
            float fc = rl(p2, kidx);
            float fd = rl(p3, kidx);
            o[0].x = fmaf(fa, v[e].x, o[0].x); o[0].y = fmaf(fa, v[e].y, o[0].y);
            o[1].x = fmaf(fb, v[e].x, o[1].x); o[1].y = fmaf(fb, v[e].y, o[1].y);
            o[2].x = fmaf(fc, v[e].x, o[2].x); o[2].y = fmaf(fc, v[e].y, o[2].y);
            o[3].x = fmaf(fd, v[e].x, o[3].x); o[3].y = fmaf(fd, v[e].y, o[3].y);
        }
    }

    const int d2 = 2 * lane;
    if (ATOMIC) {
        #pragma unroll
        for (int qq = 0; qq < 4; ++qq) {
            atomicAdd(&outp[(size_t)(qa + qq) * DD + d2],     o[qq].x);
            atomicAdd(&outp[(size_t)(qa + qq) * DD + d2 + 1], o[qq].y);
        }
    } else {
        float* base = outp + (size_t)kx * MATN;
        #pragma unroll
        for (int qq = 0; qq < 4; ++qq)
            *(float2*)&base[(size_t)(qa + qq) * DD + d2] = o[qq];
    }
}

// ---------------------------------------------------------------------------
// Fused reduce + normalize: out[q,d] = (sum_kx part[kx][q,d]) / (sum_kx psumP)
// ---------------------------------------------------------------------------
__global__ __launch_bounds__(256) void reduce_kernel(
    const float* __restrict__ part, const float* __restrict__ psumP,
    float* __restrict__ out)
{
    int t = blockIdx.x * 256 + threadIdx.x;    // 262144 float2s
    const float2* p2 = (const float2*)part;
    float2 acc = make_float2(0.f, 0.f);
    #pragma unroll
    for (int kx = 0; kx < KSPLIT; ++kx) {
        float2 v = p2[(size_t)kx * (MATN / 2) + t];
        acc.x += v.x; acc.y += v.y;
    }
    int q = t >> 6;
    float s = 0.f;
    #pragma unroll
    for (int kx = 0; kx < KSPLIT; ++kx) s += psumP[(size_t)kx * NROW + q];
    float inv = fast_rcp(s);
    ((float2*)out)[t] = make_float2(acc.x * inv, acc.y * inv);
}

// ---------------------------------------------------------------------------
__global__ __launch_bounds__(256) void norm_kernel(
    float* __restrict__ out, const float* __restrict__ psumG)
{
    int t = blockIdx.x * 256 + threadIdx.x;    // 262144 float2s
    float2* o2 = (float2*)out;
    int q = t >> 6;
    float inv = fast_rcp(psumG[q]);
    float2 v = o2[t];
    o2[t] = make_float2(v.x * inv, v.y * inv);
}

// ---------------------------------------------------------------------------
extern "C" void kernel_launch(void* const* d_in, const int* in_sizes, int n_in,
                              void* d_out, int out_size, void* d_ws, size_t ws_size,
                              hipStream_t stream) {
    const float* query = (const float*)d_in[0];
    const float* key_  = (const float*)d_in[1];
    const float* value = (const float*)d_in[2];
    const float* Wq    = (const float*)d_in[3];
    const float* bq    = (const float*)d_in[4];
    const float* Wk    = (const float*)d_in[5];
    const float* bk    = (const float*)d_in[6];
    const float* Wv    = (const float*)d_in[7];
    const float* bv    = (const float*)d_in[8];
    const float* wd    = (const float*)d_in[9];
    // d_in[10]/[12]/[14] = b_delta/b_sigma/b_theta: softmax-invariant, dropped
    const float* wsg   = (const float*)d_in[11];
    const float* wtt   = (const float*)d_in[13];
    float* ws = (float*)d_ws;
    float* out = (float*)d_out;

    // ws layout: Eq | Ek | V | w^(128) | psumP(8*NROW) | part(8*MATN)
    const size_t off_psum = (size_t)3 * MATN + 128;
    const size_t off_part = off_psum + (size_t)KSPLIT * NROW;
    const size_t need = (off_part + (size_t)KSPLIT * MATN) * sizeof(float);

    proj_kernel<<<384, 256, 0, stream>>>(query, key_, value,
                                         Wq, bq, Wk, bk, Wv, bv,
                                         wd, wsg, wtt, ws);
    if (ws_size >= need) {
        float* psumP = ws + off_psum;
        float* part  = ws + off_part;
        attn_kernel<false><<<1024, 512, 0, stream>>>(ws, part, psumP);
        reduce_kernel<<<1024, 256, 0, stream>>>(part, psumP, out);
    } else {
        float* psumG = ws + off_psum;
        hipMemsetAsync(out, 0, (size_t)out_size * sizeof(float), stream);
        hipMemsetAsync(psumG, 0, (size_t)NROW * sizeof(float), stream);
        attn_kernel<true><<<1024, 512, 0, stream>>>(ws, out, psumG);
        norm_kernel<<<1024, 256, 0, stream>>>(out, psumG);
    }
}